// Round 1
// baseline (15009.210 us; speedup 1.0000x reference)
//
#include <hip/hip_runtime.h>
#include <cstddef>

#define NBATCH 16
#define NSIDE  512
#define NT     (NBATCH * NSIDE * NSIDE)   // 4,194,304 complex elements per field
#define NLINES 8                           // FFT lines per workgroup
#define LSTRIDE 577                        // padded float2 stride per line in LDS

// sigma = tau = float32(0.97/3)
__device__ __constant__ float c_dummy; // (nothing)

constexpr float SIGMA = (float)(0.97 / 3.0);
constexpr float TAU   = (float)(0.97 / 3.0);
constexpr float INV1S = (float)(1.0 / (1.0 + 0.97 / 3.0));
constexpr float INV_N = 1.0f / 512.0f;

// ---------- complex helpers ----------
__device__ __forceinline__ float2 cadd(float2 a, float2 b){ return make_float2(a.x+b.x, a.y+b.y); }
__device__ __forceinline__ float2 csub(float2 a, float2 b){ return make_float2(a.x-b.x, a.y-b.y); }
__device__ __forceinline__ float2 cmul(float2 a, float2 b){ return make_float2(a.x*b.x - a.y*b.y, a.x*b.y + a.y*b.x); }

// padded LDS slot: +1 float2 every 8 slots (fixes stage-2/3 bank conflicts)
__device__ __forceinline__ int SL(int s){ return s + (s >> 3); }
// base-8 3-digit reversal of a 9-bit index (swap outer digits)
__device__ __forceinline__ int rev9(int s){ return ((s & 7) << 6) | (s & 56) | (s >> 6); }

// 8-point DFT, y_t = sum_j v_j * exp(S * 2*pi*i * j*t / 8).  S=-1 fwd, S=+1 adjoint.
template<int S>
__device__ __forceinline__ void dft8(float2 v[8]){
  const float RS = 0.70710678118654752440f;
  float2 a0 = cadd(v[0], v[4]), a4 = csub(v[0], v[4]);
  float2 a1 = cadd(v[1], v[5]), a5 = csub(v[1], v[5]);
  float2 a2 = cadd(v[2], v[6]), a6 = csub(v[2], v[6]);
  float2 a3 = cadd(v[3], v[7]), a7 = csub(v[3], v[7]);
  a5 = cmul(a5, make_float2(RS, (float)S * RS));
  a6 = make_float2(-(float)S * a6.y, (float)S * a6.x);          // * (0, S)
  a7 = cmul(a7, make_float2(-RS, (float)S * RS));
  float2 b0 = cadd(a0, a2), b2 = csub(a0, a2);
  float2 b1 = cadd(a1, a3), b3 = csub(a1, a3);
  b3 = make_float2(-(float)S * b3.y, (float)S * b3.x);
  v[0] = cadd(b0, b1); v[4] = csub(b0, b1);
  v[2] = cadd(b2, b3); v[6] = csub(b2, b3);
  float2 c0 = cadd(a4, a6), c2 = csub(a4, a6);
  float2 c1 = cadd(a5, a7), c3 = csub(a5, a7);
  c3 = make_float2(-(float)S * c3.y, (float)S * c3.x);
  v[1] = cadd(c0, c1); v[5] = csub(c0, c1);
  v[3] = cadd(c2, c3); v[7] = csub(c2, c3);
}

// Forward 512-point DIF FFT on two LDS lines (one wave, lane l = 0..63).
// Natural-order input at slots SL(n); output X[rev9(s)] at slots SL(s).
// Contains 2 internal __syncthreads() - must be called by ALL threads of the block.
__device__ __forceinline__ void fft_fwd_pair(float2* __restrict__ A, float2* __restrict__ B, int l){
  float2 va[8], vb[8];
  // stage 1: groups {l + 64j}, twiddle W512^{l*t}
  #pragma unroll
  for(int j = 0; j < 8; j++){ int s = SL(l + 64*j); va[j] = A[s]; vb[j] = B[s]; }
  dft8<-1>(va); dft8<-1>(vb);
  #pragma unroll
  for(int t = 1; t < 8; t++){
    float sn, cs;
    __sincosf((-6.283185307179586f / 512.0f) * (float)(l * t), &sn, &cs);
    float2 w = make_float2(cs, sn);
    va[t] = cmul(va[t], w); vb[t] = cmul(vb[t], w);
  }
  #pragma unroll
  for(int t = 0; t < 8; t++){ int s = SL(t*64 + l); A[s] = va[t]; B[s] = vb[t]; }
  __syncthreads();
  // stage 2: t = l>>3, m = l&7, groups {64t + m + 8j}, twiddle W64^{m*t2}
  int tg = l >> 3, m = l & 7;
  #pragma unroll
  for(int j = 0; j < 8; j++){ int s = SL(tg*64 + m + 8*j); va[j] = A[s]; vb[j] = B[s]; }
  dft8<-1>(va); dft8<-1>(vb);
  #pragma unroll
  for(int t = 1; t < 8; t++){
    float sn, cs;
    __sincosf((-6.283185307179586f / 64.0f) * (float)(m * t), &sn, &cs);
    float2 w = make_float2(cs, sn);
    va[t] = cmul(va[t], w); vb[t] = cmul(vb[t], w);
  }
  #pragma unroll
  for(int t = 0; t < 8; t++){ int s = SL(tg*64 + t*8 + m); A[s] = va[t]; B[s] = vb[t]; }
  __syncthreads();
  // stage 3: groups {8l + j}, no twiddle
  #pragma unroll
  for(int j = 0; j < 8; j++){ int s = SL(8*l + j); va[j] = A[s]; vb[j] = B[s]; }
  dft8<-1>(va); dft8<-1>(vb);
  #pragma unroll
  for(int t = 0; t < 8; t++){ int s = SL(8*l + t); A[s] = va[t]; B[s] = vb[t]; }
}

// Adjoint (unnormalized inverse) 512-point FFT: digit-reversed input at slots,
// natural-order spatial output at slots SL(n).  Exact adjoint of fft_fwd_pair.
__device__ __forceinline__ void fft_inv_pair(float2* __restrict__ A, float2* __restrict__ B, int l){
  float2 va[8], vb[8];
  // stage 3^H
  #pragma unroll
  for(int j = 0; j < 8; j++){ int s = SL(8*l + j); va[j] = A[s]; vb[j] = B[s]; }
  dft8<1>(va); dft8<1>(vb);
  #pragma unroll
  for(int t = 0; t < 8; t++){ int s = SL(8*l + t); A[s] = va[t]; B[s] = vb[t]; }
  __syncthreads();
  // stage 2^H: twiddle-before-butterfly, conj twiddles
  int tg = l >> 3, m = l & 7;
  #pragma unroll
  for(int j = 0; j < 8; j++){ int s = SL(tg*64 + 8*j + m); va[j] = A[s]; vb[j] = B[s]; }
  #pragma unroll
  for(int j = 1; j < 8; j++){
    float sn, cs;
    __sincosf((6.283185307179586f / 64.0f) * (float)(m * j), &sn, &cs);
    float2 w = make_float2(cs, sn);
    va[j] = cmul(va[j], w); vb[j] = cmul(vb[j], w);
  }
  dft8<1>(va); dft8<1>(vb);
  #pragma unroll
  for(int j = 0; j < 8; j++){ int s = SL(tg*64 + m + 8*j); A[s] = va[j]; B[s] = vb[j]; }
  __syncthreads();
  // stage 1^H
  #pragma unroll
  for(int t = 0; t < 8; t++){ int s = SL(t*64 + l); va[t] = A[s]; vb[t] = B[s]; }
  #pragma unroll
  for(int t = 1; t < 8; t++){
    float sn, cs;
    __sincosf((6.283185307179586f / 512.0f) * (float)(l * t), &sn, &cs);
    float2 w = make_float2(cs, sn);
    va[t] = cmul(va[t], w); vb[t] = cmul(vb[t], w);
  }
  dft8<1>(va); dft8<1>(vb);
  #pragma unroll
  for(int j = 0; j < 8; j++){ int s = SL(l + 64*j); A[s] = va[j]; B[s] = vb[j]; }
}

// ---------------- K1: forward row FFT of S*xbar/512 -> U (transposed, slot order) ------------
__global__ __launch_bounds__(256) void k_fwd_rows(const float2* __restrict__ xbar, float2* __restrict__ U){
  __shared__ float2 lds[NLINES * LSTRIDE];
  int b = blockIdx.x >> 6, r0 = (blockIdx.x & 63) << 3;
  int t = threadIdx.x;
  int rr = t >> 5, col = t & 31;
  const float2* src = xbar + ((size_t)(b * 512 + r0) << 9);
  #pragma unroll
  for(int k = 0; k < 16; k++){
    int c = col + 32 * k;
    float2 v = src[(rr << 9) + c];
    float sc = ((r0 + rr + c) & 1) ? -INV_N : INV_N;
    v.x *= sc; v.y *= sc;
    lds[rr * LSTRIDE + SL(c)] = v;
  }
  __syncthreads();
  int wv = t >> 6, l = t & 63;
  fft_fwd_pair(&lds[wv * LSTRIDE], &lds[(wv + 4) * LSTRIDE], l);
  __syncthreads();
  // transposed store: U[b][s][r0+rr]
  float2* dst = U + ((size_t)b << 18) + r0;
  int rr2 = t & 7, s0 = t >> 3;
  #pragma unroll
  for(int k = 0; k < 16; k++){
    int s = s0 + 32 * k;
    dst[((size_t)s << 9) + rr2] = lds[rr2 * LSTRIDE + SL(s)];
  }
}

// ------------- K2: column fwd FFT + p1 prox + mask + column inv FFT -> V ---------------------
__global__ __launch_bounds__(256) void k_cols(const float2* __restrict__ U, float2* __restrict__ p1,
                                              const float2* __restrict__ yk, const float* __restrict__ mperm,
                                              float2* __restrict__ V){
  __shared__ float2 lds[NLINES * LSTRIDE];
  int b = blockIdx.x >> 6, cs0 = (blockIdx.x & 63) << 3;
  int t = threadIdx.x;
  int rr = t >> 5, col = t & 31;
  const float2* src = U + ((size_t)(b * 512 + cs0) << 9);
  #pragma unroll
  for(int k = 0; k < 16; k++){
    int r = col + 32 * k;
    lds[rr * LSTRIDE + SL(r)] = src[(rr << 9) + r];
  }
  __syncthreads();
  int wv = t >> 6, l = t & 63;
  fft_fwd_pair(&lds[wv * LSTRIDE], &lds[(wv + 4) * LSTRIDE], l);
  __syncthreads();
  // p1' = (p1' + sigma*(m*K - y')) / (1+sigma);  LDS <- m*p1'
  float2* p1p = p1 + ((size_t)(b * 512 + cs0) << 9);
  const float2* yp = yk + ((size_t)(b * 512 + cs0) << 9);
  const float* mp = mperm + ((size_t)cs0 << 9);
  #pragma unroll
  for(int k = 0; k < 16; k++){
    int s = col + 32 * k;
    float2 K = lds[rr * LSTRIDE + SL(s)];
    float2 p = p1p[(rr << 9) + s];
    float2 yv = yp[(rr << 9) + s];
    float m = mp[(rr << 9) + s];
    float2 pn;
    pn.x = (p.x + SIGMA * (m * K.x - yv.x)) * INV1S;
    pn.y = (p.y + SIGMA * (m * K.y - yv.y)) * INV1S;
    p1p[(rr << 9) + s] = pn;
    lds[rr * LSTRIDE + SL(s)] = make_float2(m * pn.x, m * pn.y);
  }
  __syncthreads();
  fft_inv_pair(&lds[wv * LSTRIDE], &lds[(wv + 4) * LSTRIDE], l);
  __syncthreads();
  // transposed store: V[b][r][cs0+rr]
  float2* dst = V + ((size_t)b << 18) + cs0;
  int rr2 = t & 7, s0 = t >> 3;
  #pragma unroll
  for(int k = 0; k < 16; k++){
    int s = s0 + 32 * k;
    dst[((size_t)s << 9) + rr2] = lds[rr2 * LSTRIDE + SL(s)];
  }
}

// ---------------- K2b: TV dual update (p2 clip) ----------------------------------------------
__global__ __launch_bounds__(256) void k_p2(const float2* __restrict__ xbar, float2* __restrict__ p2h,
                                            float2* __restrict__ p2w, const float* __restrict__ lam){
  int i = blockIdx.x * 256 + threadIdx.x;
  int c = i & 511, r = (i >> 9) & 511;
  int idn = (r < 511) ? i + 512 : i - (511 << 9);   // (r+1 mod 512, c)
  int irt = (c < 511) ? i + 1   : i - 511;          // (r, c+1 mod 512)
  float2 xc = xbar[i];
  float2 xd = xbar[idn];
  float2 xr = xbar[irt];
  float lv = lam[i];
  float2 qh = p2h[i], qw = p2w[i];
  qh.x += SIGMA * (xd.x - xc.x); qh.y += SIGMA * (xd.y - xc.y);
  qw.x += SIGMA * (xr.x - xc.x); qw.y += SIGMA * (xr.y - xc.y);
  qh.x = fminf(fmaxf(qh.x, -lv), lv); qh.y = fminf(fmaxf(qh.y, -lv), lv);
  qw.x = fminf(fmaxf(qw.x, -lv), lv); qw.y = fminf(fmaxf(qw.y, -lv), lv);
  p2h[i] = qh; p2w[i] = qw;
}

// ---------------- K3: inverse row FFT + S/512 + divergence + primal update -------------------
__global__ __launch_bounds__(256) void k_inv_rows(const float2* __restrict__ V, const float2* __restrict__ p2h,
                                                  const float2* __restrict__ p2w, float2* __restrict__ x,
                                                  float2* __restrict__ xbar){
  __shared__ float2 lds[NLINES * LSTRIDE];
  int b = blockIdx.x >> 6, r0 = (blockIdx.x & 63) << 3;
  int t = threadIdx.x;
  int rr = t >> 5, col = t & 31;
  const float2* src = V + ((size_t)(b * 512 + r0) << 9);
  #pragma unroll
  for(int k = 0; k < 16; k++){
    int cs = col + 32 * k;
    lds[rr * LSTRIDE + SL(cs)] = src[(rr << 9) + cs];
  }
  __syncthreads();
  int wv = t >> 6, l = t & 63;
  fft_inv_pair(&lds[wv * LSTRIDE], &lds[(wv + 4) * LSTRIDE], l);
  __syncthreads();
  int r = r0 + rr;
  size_t base   = ((size_t)(b * 512 + r) << 9);
  size_t baseUp = ((size_t)(b * 512 + ((r - 1) & 511)) << 9);
  #pragma unroll
  for(int k = 0; k < 16; k++){
    int c = col + 32 * k;
    float2 v = lds[rr * LSTRIDE + SL(c)];
    float sc = ((r + c) & 1) ? -INV_N : INV_N;
    float2 ph  = p2h[base + c];
    float2 phu = p2h[baseUp + c];
    float2 pw  = p2w[base + c];
    float2 pwl = p2w[base + ((c - 1) & 511)];
    float gx = sc * v.x + (phu.x - ph.x) + (pwl.x - pw.x);
    float gy = sc * v.y + (phu.y - ph.y) + (pwl.y - pw.y);
    float2 xo = x[base + c];
    float2 xn = make_float2(xo.x - TAU * gx, xo.y - TAU * gy);
    x[base + c] = xn;
    xbar[base + c] = make_float2(2.0f * xn.x - xo.x, 2.0f * xn.y - xo.y);
  }
}

// ---------------- init kernels ---------------------------------------------------------------
__global__ __launch_bounds__(256) void k_init_x(const float* __restrict__ ir, const float* __restrict__ ii,
                                                float2* __restrict__ x, float2* __restrict__ xbar){
  int i = blockIdx.x * 256 + threadIdx.x;
  float2 v = make_float2(ir[i], ii[i]);
  x[i] = v; xbar[i] = v;
}

// y' in digit-reversed, S-multiplied k-space layout: y'[b][cs][ks] = (-1)^{kr+c} y[b][kr][c]
__global__ __launch_bounds__(256) void k_init_y(const float* __restrict__ kr, const float* __restrict__ ki,
                                                float2* __restrict__ yk){
  int i = blockIdx.x * 256 + threadIdx.x;
  int ks = i & 511, cs = (i >> 9) & 511, b = i >> 18;
  int krow = rev9(ks), c = rev9(cs);
  size_t j = ((size_t)(b * 512 + krow) << 9) + c;
  float s = ((krow + c) & 1) ? -1.0f : 1.0f;
  yk[i] = make_float2(s * kr[j], s * ki[j]);
}

__global__ __launch_bounds__(256) void k_init_m(const int* __restrict__ mask, float* __restrict__ mperm){
  int i = blockIdx.x * 256 + threadIdx.x;   // i = cs*512 + ks
  int ks = i & 511, cs = i >> 9;
  mperm[i] = (float)mask[(rev9(ks) << 9) + rev9(cs)];
}

// ---------------- launcher -------------------------------------------------------------------
extern "C" void kernel_launch(void* const* d_in, const int* in_sizes, int n_in,
                              void* d_out, int out_size, void* d_ws, size_t ws_size,
                              hipStream_t stream){
  const float* ir  = (const float*)d_in[0];
  const float* ii  = (const float*)d_in[1];
  const float* kdr = (const float*)d_in[2];
  const float* kdi = (const float*)d_in[3];
  const float* lam = (const float*)d_in[4];
  const int*  mask = (const int*)d_in[5];
  float2* x = (float2*)d_out;                 // x lives in d_out (interleaved re,im)

  char* ws = (char*)d_ws;
  float2* p1   = (float2*)ws;                 // dual p1' (S-space, digit-rev both dims)
  float2* p2h  = p1  + NT;
  float2* p2w  = p2h + NT;
  float2* xbar = p2w + NT;
  float2* yk   = xbar + NT;
  float2* U    = yk  + NT;
  float2* V    = U   + NT;
  float*  mperm = (float*)(V + NT);
  // total ws use: 7*32MB + 1MB = ~236MB

  // zero duals (p1, p2h, p2w are contiguous)
  hipMemsetAsync(p1, 0, (size_t)3 * NT * sizeof(float2), stream);
  k_init_x<<<NT / 256, 256, 0, stream>>>(ir, ii, x, xbar);
  k_init_y<<<NT / 256, 256, 0, stream>>>(kdr, kdi, yk);
  k_init_m<<<(512 * 512) / 256, 256, 0, stream>>>(mask, mperm);

  for(int it = 0; it < 128; it++){
    k_fwd_rows<<<1024, 256, 0, stream>>>(xbar, U);
    k_cols<<<1024, 256, 0, stream>>>(U, p1, yk, mperm, V);
    k_p2<<<NT / 256, 256, 0, stream>>>(xbar, p2h, p2w, lam);
    k_inv_rows<<<1024, 256, 0, stream>>>(V, p2h, p2w, x, xbar);
  }
}

// Round 2
// 12111.826 us; speedup vs baseline: 1.2392x; 1.2392x over previous
//
#include <hip/hip_runtime.h>
#include <cstddef>

#define NBATCH 16
#define NSIDE  512
#define NT     (NBATCH * NSIDE * NSIDE)   // 4,194,304 complex elements per field
#define NLINES 8                           // FFT lines per workgroup
#define LSTRIDE 577                        // padded float2 stride per line in LDS
#define APACK  (512 * 512)                 // packed capacity (worst case all-active)

constexpr float SIGMA = (float)(0.97 / 3.0);
constexpr float TAU   = (float)(0.97 / 3.0);
constexpr float INV1S = (float)(1.0 / (1.0 + 0.97 / 3.0));
constexpr float INV_N = 1.0f / 512.0f;

// ---------- complex helpers ----------
__device__ __forceinline__ float2 cadd(float2 a, float2 b){ return make_float2(a.x+b.x, a.y+b.y); }
__device__ __forceinline__ float2 csub(float2 a, float2 b){ return make_float2(a.x-b.x, a.y-b.y); }
__device__ __forceinline__ float2 cmul(float2 a, float2 b){ return make_float2(a.x*b.x - a.y*b.y, a.x*b.y + a.y*b.x); }

// padded LDS slot: +1 float2 every 8 slots
__device__ __forceinline__ int SL(int s){ return s + (s >> 3); }
// base-8 3-digit reversal of a 9-bit index
__device__ __forceinline__ int rev9(int s){ return ((s & 7) << 6) | (s & 56) | (s >> 6); }

template<int S>
__device__ __forceinline__ void dft8(float2 v[8]){
  const float RS = 0.70710678118654752440f;
  float2 a0 = cadd(v[0], v[4]), a4 = csub(v[0], v[4]);
  float2 a1 = cadd(v[1], v[5]), a5 = csub(v[1], v[5]);
  float2 a2 = cadd(v[2], v[6]), a6 = csub(v[2], v[6]);
  float2 a3 = cadd(v[3], v[7]), a7 = csub(v[3], v[7]);
  a5 = cmul(a5, make_float2(RS, (float)S * RS));
  a6 = make_float2(-(float)S * a6.y, (float)S * a6.x);
  a7 = cmul(a7, make_float2(-RS, (float)S * RS));
  float2 b0 = cadd(a0, a2), b2 = csub(a0, a2);
  float2 b1 = cadd(a1, a3), b3 = csub(a1, a3);
  b3 = make_float2(-(float)S * b3.y, (float)S * b3.x);
  v[0] = cadd(b0, b1); v[4] = csub(b0, b1);
  v[2] = cadd(b2, b3); v[6] = csub(b2, b3);
  float2 c0 = cadd(a4, a6), c2 = csub(a4, a6);
  float2 c1 = cadd(a5, a7), c3 = csub(a5, a7);
  c3 = make_float2(-(float)S * c3.y, (float)S * c3.x);
  v[1] = cadd(c0, c1); v[5] = csub(c0, c1);
  v[3] = cadd(c2, c3); v[7] = csub(c2, c3);
}

// Forward 512-pt DIF FFT on two LDS lines (one wave). Natural in, digit-rev out.
__device__ __forceinline__ void fft_fwd_pair(float2* __restrict__ A, float2* __restrict__ B, int l){
  float2 va[8], vb[8];
  #pragma unroll
  for(int j = 0; j < 8; j++){ int s = SL(l + 64*j); va[j] = A[s]; vb[j] = B[s]; }
  dft8<-1>(va); dft8<-1>(vb);
  #pragma unroll
  for(int t = 1; t < 8; t++){
    float sn, cs;
    __sincosf((-6.283185307179586f / 512.0f) * (float)(l * t), &sn, &cs);
    float2 w = make_float2(cs, sn);
    va[t] = cmul(va[t], w); vb[t] = cmul(vb[t], w);
  }
  #pragma unroll
  for(int t = 0; t < 8; t++){ int s = SL(t*64 + l); A[s] = va[t]; B[s] = vb[t]; }
  __syncthreads();
  int tg = l >> 3, m = l & 7;
  #pragma unroll
  for(int j = 0; j < 8; j++){ int s = SL(tg*64 + m + 8*j); va[j] = A[s]; vb[j] = B[s]; }
  dft8<-1>(va); dft8<-1>(vb);
  #pragma unroll
  for(int t = 1; t < 8; t++){
    float sn, cs;
    __sincosf((-6.283185307179586f / 64.0f) * (float)(m * t), &sn, &cs);
    float2 w = make_float2(cs, sn);
    va[t] = cmul(va[t], w); vb[t] = cmul(vb[t], w);
  }
  #pragma unroll
  for(int t = 0; t < 8; t++){ int s = SL(tg*64 + t*8 + m); A[s] = va[t]; B[s] = vb[t]; }
  __syncthreads();
  #pragma unroll
  for(int j = 0; j < 8; j++){ int s = SL(8*l + j); va[j] = A[s]; vb[j] = B[s]; }
  dft8<-1>(va); dft8<-1>(vb);
  #pragma unroll
  for(int t = 0; t < 8; t++){ int s = SL(8*l + t); A[s] = va[t]; B[s] = vb[t]; }
}

// Adjoint 512-pt FFT: digit-rev in, natural out. Exact adjoint of fft_fwd_pair.
__device__ __forceinline__ void fft_inv_pair(float2* __restrict__ A, float2* __restrict__ B, int l){
  float2 va[8], vb[8];
  #pragma unroll
  for(int j = 0; j < 8; j++){ int s = SL(8*l + j); va[j] = A[s]; vb[j] = B[s]; }
  dft8<1>(va); dft8<1>(vb);
  #pragma unroll
  for(int t = 0; t < 8; t++){ int s = SL(8*l + t); A[s] = va[t]; B[s] = vb[t]; }
  __syncthreads();
  int tg = l >> 3, m = l & 7;
  #pragma unroll
  for(int j = 0; j < 8; j++){ int s = SL(tg*64 + 8*j + m); va[j] = A[s]; vb[j] = B[s]; }
  #pragma unroll
  for(int j = 1; j < 8; j++){
    float sn, cs;
    __sincosf((6.283185307179586f / 64.0f) * (float)(m * j), &sn, &cs);
    float2 w = make_float2(cs, sn);
    va[j] = cmul(va[j], w); vb[j] = cmul(vb[j], w);
  }
  dft8<1>(va); dft8<1>(vb);
  #pragma unroll
  for(int j = 0; j < 8; j++){ int s = SL(tg*64 + m + 8*j); A[s] = va[j]; B[s] = vb[j]; }
  __syncthreads();
  #pragma unroll
  for(int t = 0; t < 8; t++){ int s = SL(t*64 + l); va[t] = A[s]; vb[t] = B[s]; }
  #pragma unroll
  for(int t = 1; t < 8; t++){
    float sn, cs;
    __sincosf((6.283185307179586f / 512.0f) * (float)(l * t), &sn, &cs);
    float2 w = make_float2(cs, sn);
    va[t] = cmul(va[t], w); vb[t] = cmul(vb[t], w);
  }
  dft8<1>(va); dft8<1>(vb);
  #pragma unroll
  for(int j = 0; j < 8; j++){ int s = SL(l + 64*j); A[s] = va[j]; B[s] = vb[j]; }
}

// ---------------- prologue: forward row FFT of S*xbar/512 -> U (transposed) ------------------
__global__ __launch_bounds__(256) void k_fwd_rows(const float2* __restrict__ xbar, float2* __restrict__ U){
  __shared__ float2 lds[NLINES * LSTRIDE];
  int b = blockIdx.x >> 6, r0 = (blockIdx.x & 63) << 3;
  int t = threadIdx.x;
  int rr = t >> 5, col = t & 31;
  const float2* src = xbar + ((size_t)(b * 512 + r0) << 9);
  #pragma unroll
  for(int k = 0; k < 16; k++){
    int c = col + 32 * k;
    float2 v = src[(rr << 9) + c];
    float sc = ((r0 + rr + c) & 1) ? -INV_N : INV_N;
    v.x *= sc; v.y *= sc;
    lds[rr * LSTRIDE + SL(c)] = v;
  }
  __syncthreads();
  int wv = t >> 6, l = t & 63;
  fft_fwd_pair(&lds[wv * LSTRIDE], &lds[(wv + 4) * LSTRIDE], l);
  __syncthreads();
  float2* dst = U + ((size_t)b << 18) + r0;
  int rr2 = t & 7, s0 = t >> 3;
  #pragma unroll
  for(int k = 0; k < 16; k++){
    int s = s0 + 32 * k;
    dst[((size_t)s << 9) + rr2] = lds[rr2 * LSTRIDE + SL(s)];
  }
}

// ------------- K2: column fwd FFT + packed p1 prox + column inv FFT -> V ---------------------
__global__ __launch_bounds__(256) void k_cols2(const float2* __restrict__ U, float2* __restrict__ p1p,
                                               const float2* __restrict__ yp, const int* __restrict__ idx,
                                               const int* __restrict__ cnt, float2* __restrict__ V){
  __shared__ float2 lds[NLINES * LSTRIDE];
  int b = blockIdx.x >> 6, cs0 = (blockIdx.x & 63) << 3;
  int t = threadIdx.x;
  int rr = t >> 5, col = t & 31;
  const float2* src = U + ((size_t)(b * 512 + cs0) << 9);
  #pragma unroll
  for(int k = 0; k < 16; k++){
    int r = col + 32 * k;
    lds[rr * LSTRIDE + SL(r)] = src[(rr << 9) + r];
  }
  __syncthreads();
  int wv = t >> 6, l = t & 63;
  fft_fwd_pair(&lds[wv * LSTRIDE], &lds[(wv + 4) * LSTRIDE], l);
  __syncthreads();
  // packed p1 update: line g handles column cs0+g, segment [cs*512, cs*512+cnt[cs])
  int g = rr, lane = col;
  int cs = cs0 + g;
  int jbase = cs << 9;
  int jcnt = cnt[cs];
  size_t boff = (size_t)b * APACK;
  int ksi[16]; float2 pn[16];
  #pragma unroll
  for(int tt = 0; tt < 16; tt++){
    int jj = lane + 32 * tt;
    bool act = jj < jcnt;
    int j = jbase + (act ? jj : 0);
    int ks = act ? idx[j] : 0;
    float2 K = lds[g * LSTRIDE + SL(ks)];
    float2 yv = yp[boff + j];
    float2 p  = p1p[boff + j];
    float2 v;
    v.x = (p.x + SIGMA * (K.x - yv.x)) * INV1S;
    v.y = (p.y + SIGMA * (K.y - yv.y)) * INV1S;
    if(act) p1p[boff + j] = v;
    ksi[tt] = act ? ks : -1;
    pn[tt] = v;
  }
  __syncthreads();
  #pragma unroll
  for(int k = 0; k < 16; k++) lds[rr * LSTRIDE + SL(col + 32 * k)] = make_float2(0.0f, 0.0f);
  __syncthreads();
  #pragma unroll
  for(int tt = 0; tt < 16; tt++) if(ksi[tt] >= 0) lds[g * LSTRIDE + SL(ksi[tt])] = pn[tt];
  __syncthreads();
  fft_inv_pair(&lds[wv * LSTRIDE], &lds[(wv + 4) * LSTRIDE], l);
  __syncthreads();
  float2* dst = V + ((size_t)b << 18) + cs0;
  int rr2 = t & 7, s0 = t >> 3;
  #pragma unroll
  for(int k = 0; k < 16; k++){
    int s = s0 + 32 * k;
    dst[((size_t)s << 9) + rr2] = lds[rr2 * LSTRIDE + SL(s)];
  }
}

// ---------------- K2b: TV dual update (p2 clip) ----------------------------------------------
__global__ __launch_bounds__(256) void k_p2(const float2* __restrict__ xbar, float2* __restrict__ p2h,
                                            float2* __restrict__ p2w, const float* __restrict__ lam){
  int i = blockIdx.x * 256 + threadIdx.x;
  int c = i & 511, r = (i >> 9) & 511;
  int idn = (r < 511) ? i + 512 : i - (511 << 9);
  int irt = (c < 511) ? i + 1   : i - 511;
  float2 xc = xbar[i];
  float2 xd = xbar[idn];
  float2 xr = xbar[irt];
  float lv = lam[i];
  float2 qh = p2h[i], qw = p2w[i];
  qh.x += SIGMA * (xd.x - xc.x); qh.y += SIGMA * (xd.y - xc.y);
  qw.x += SIGMA * (xr.x - xc.x); qw.y += SIGMA * (xr.y - xc.y);
  qh.x = fminf(fmaxf(qh.x, -lv), lv); qh.y = fminf(fmaxf(qh.y, -lv), lv);
  qw.x = fminf(fmaxf(qw.x, -lv), lv); qw.y = fminf(fmaxf(qw.y, -lv), lv);
  p2h[i] = qh; p2w[i] = qw;
}

// ------- K3+K1 fused: row IFFT + S/512 + divergence + primal update + row FFT -> U -----------
__global__ __launch_bounds__(256) void k_mega3(const float2* __restrict__ V, const float2* __restrict__ p2h,
                                               const float2* __restrict__ p2w, float2* __restrict__ x,
                                               float2* __restrict__ xbar, float2* __restrict__ U, int last){
  __shared__ float2 lds[NLINES * LSTRIDE];
  int b = blockIdx.x >> 6, r0 = (blockIdx.x & 63) << 3;
  int t = threadIdx.x;
  int rr = t >> 5, col = t & 31;
  const float2* src = V + ((size_t)(b * 512 + r0) << 9);
  #pragma unroll
  for(int k = 0; k < 16; k++){
    int cs = col + 32 * k;
    lds[rr * LSTRIDE + SL(cs)] = src[(rr << 9) + cs];
  }
  __syncthreads();
  int wv = t >> 6, l = t & 63;
  fft_inv_pair(&lds[wv * LSTRIDE], &lds[(wv + 4) * LSTRIDE], l);
  __syncthreads();
  int r = r0 + rr;
  size_t base   = ((size_t)(b * 512 + r) << 9);
  size_t baseUp = ((size_t)(b * 512 + ((r - 1) & 511)) << 9);
  #pragma unroll
  for(int k = 0; k < 16; k++){
    int c = col + 32 * k;
    int cl = (c - 1) & 511;
    float2 v = lds[rr * LSTRIDE + SL(c)];
    float sc = ((r + c) & 1) ? -INV_N : INV_N;
    float2 ph  = p2h[base + c];
    float2 phu = p2h[baseUp + c];
    float2 pw  = p2w[base + c];
    float2 pwl = p2w[base + cl];
    float gx = sc * v.x + (phu.x - ph.x) + (pwl.x - pw.x);
    float gy = sc * v.y + (phu.y - ph.y) + (pwl.y - pw.y);
    float2 xo = x[base + c];
    float2 xn = make_float2(xo.x - TAU * gx, xo.y - TAU * gy);
    x[base + c] = xn;
    float2 xb2 = make_float2(2.0f * xn.x - xo.x, 2.0f * xn.y - xo.y);
    xbar[base + c] = xb2;
    lds[rr * LSTRIDE + SL(c)] = make_float2(sc * xb2.x, sc * xb2.y);  // S*xbar/512 for next fwd FFT
  }
  if(last) return;
  __syncthreads();
  fft_fwd_pair(&lds[wv * LSTRIDE], &lds[(wv + 4) * LSTRIDE], l);
  __syncthreads();
  float2* dst = U + ((size_t)b << 18) + r0;
  int rr2 = t & 7, s0 = t >> 3;
  #pragma unroll
  for(int k = 0; k < 16; k++){
    int s = s0 + 32 * k;
    dst[((size_t)s << 9) + rr2] = lds[rr2 * LSTRIDE + SL(s)];
  }
}

// ---------------- init kernels ---------------------------------------------------------------
__global__ __launch_bounds__(256) void k_init_x(const float* __restrict__ ir, const float* __restrict__ ii,
                                                float2* __restrict__ x, float2* __restrict__ xbar){
  int i = blockIdx.x * 256 + threadIdx.x;
  float2 v = make_float2(ir[i], ii[i]);
  x[i] = v; xbar[i] = v;
}

// Build per-column packed index list + packed y' (digit-rev, S-folded) for active mask entries.
__global__ __launch_bounds__(256) void k_pack(const int* __restrict__ mask, const float* __restrict__ kr,
                                              const float* __restrict__ ki, int* __restrict__ idx,
                                              int* __restrict__ cnt, float2* __restrict__ yp){
  __shared__ int wcnt[8];
  int cs = blockIdx.x;
  int t = threadIdx.x, lane = t & 63, wv = t >> 6;
  int csr = rev9(cs);
  int jbase = cs << 9;
  #pragma unroll
  for(int rnd = 0; rnd < 2; rnd++){
    int ks = t + 256 * rnd;
    int ksr = rev9(ks);
    int pred = (mask[(ksr << 9) + csr] != 0) ? 1 : 0;
    unsigned long long bal = __ballot(pred);
    if(lane == 0) wcnt[4 * rnd + wv] = (int)__popcll(bal);
    __syncthreads();
    int pre = 0;
    for(int w = 0; w < wv; w++) pre += wcnt[4 * rnd + w];
    int roundbase = (rnd == 1) ? (wcnt[0] + wcnt[1] + wcnt[2] + wcnt[3]) : 0;
    int lpre = (int)__popcll(bal & ((1ull << lane) - 1ull));
    if(pred){
      int pos = jbase + roundbase + pre + lpre;
      idx[pos] = ks;
      float s = ((ksr + csr) & 1) ? -1.0f : 1.0f;
      for(int b = 0; b < 16; b++){
        size_t a = ((size_t)b << 18) + ((size_t)ksr << 9) + csr;
        yp[(size_t)b * APACK + pos] = make_float2(s * kr[a], s * ki[a]);
      }
    }
    __syncthreads();
  }
  if(t == 0) cnt[cs] = wcnt[0] + wcnt[1] + wcnt[2] + wcnt[3] + wcnt[4] + wcnt[5] + wcnt[6] + wcnt[7];
}

// ---------------- launcher -------------------------------------------------------------------
extern "C" void kernel_launch(void* const* d_in, const int* in_sizes, int n_in,
                              void* d_out, int out_size, void* d_ws, size_t ws_size,
                              hipStream_t stream){
  const float* ir  = (const float*)d_in[0];
  const float* ii  = (const float*)d_in[1];
  const float* kdr = (const float*)d_in[2];
  const float* kdi = (const float*)d_in[3];
  const float* lam = (const float*)d_in[4];
  const int*  mask = (const int*)d_in[5];
  float2* x = (float2*)d_out;

  char* ws = (char*)d_ws;
  float2* p1p  = (float2*)ws;               // packed p1, 32 MB cap
  float2* yp   = p1p + (size_t)APACK * 16;  // packed y',  32 MB cap
  float2* xbar = yp  + (size_t)APACK * 16;  // 32 MB
  float2* p2h  = xbar + NT;                 // 32 MB
  float2* p2w  = p2h + NT;                  // 32 MB
  float2* U    = p2w + NT;                  // 32 MB
  float2* V    = U   + NT;                  // 32 MB
  int*    idx  = (int*)(V + NT);            // 1 MB
  int*    cnt  = idx + APACK;               // 2 KB
  // total ws use: ~225 MB (same footprint as round 0)

  hipMemsetAsync(p1p, 0, (size_t)APACK * 16 * sizeof(float2), stream);
  hipMemsetAsync(p2h, 0, (size_t)2 * NT * sizeof(float2), stream);   // p2h + p2w contiguous
  k_pack<<<512, 256, 0, stream>>>(mask, kdr, kdi, idx, cnt, yp);
  k_init_x<<<NT / 256, 256, 0, stream>>>(ir, ii, x, xbar);
  k_fwd_rows<<<1024, 256, 0, stream>>>(xbar, U);

  for(int it = 0; it < 128; it++){
    k_cols2<<<1024, 256, 0, stream>>>(U, p1p, yp, idx, cnt, V);
    k_p2<<<NT / 256, 256, 0, stream>>>(xbar, p2h, p2w, lam);
    k_mega3<<<1024, 256, 0, stream>>>(V, p2h, p2w, x, xbar, U, it == 127 ? 1 : 0);
  }
}

// Round 3
// 8455.035 us; speedup vs baseline: 1.7752x; 1.4325x over previous
//
#include <hip/hip_runtime.h>
#include <hip/hip_fp16.h>
#include <cstddef>

#define NBATCH 16
#define NSIDE  512
#define NT     (NBATCH * NSIDE * NSIDE)   // 4,194,304 complex elements per field
#define NLINES 8                           // FFT lines per workgroup
#define LSTRIDE 577                        // padded float2 stride per line in LDS
#define APACK  (512 * 512)                 // packed capacity (worst case all-active)

constexpr float SIGMA = (float)(0.97 / 3.0);
constexpr float TAU   = (float)(0.97 / 3.0);
constexpr float INV1S = (float)(1.0 / (1.0 + 0.97 / 3.0));
constexpr float INV_N = 1.0f / 512.0f;

// ---------- complex helpers ----------
__device__ __forceinline__ float2 cadd(float2 a, float2 b){ return make_float2(a.x+b.x, a.y+b.y); }
__device__ __forceinline__ float2 csub(float2 a, float2 b){ return make_float2(a.x-b.x, a.y-b.y); }
__device__ __forceinline__ float2 cmul(float2 a, float2 b){ return make_float2(a.x*b.x - a.y*b.y, a.x*b.y + a.y*b.x); }

// padded LDS slot: +1 float2 every 8 slots
__device__ __forceinline__ int SL(int s){ return s + (s >> 3); }
// base-8 3-digit reversal of a 9-bit index
__device__ __forceinline__ int rev9(int s){ return ((s & 7) << 6) | (s & 56) | (s >> 6); }

// fp16 pack/unpack
__device__ __forceinline__ unsigned h2bits(float2 v){
  __half2 h = __floats2half2_rn(v.x, v.y);
  return *reinterpret_cast<unsigned*>(&h);
}
__device__ __forceinline__ float2 bits2f(unsigned u){
  __half2 h = *reinterpret_cast<__half2*>(&u);
  return __half22float2(h);
}

template<int S>
__device__ __forceinline__ void dft8(float2 v[8]){
  const float RS = 0.70710678118654752440f;
  float2 a0 = cadd(v[0], v[4]), a4 = csub(v[0], v[4]);
  float2 a1 = cadd(v[1], v[5]), a5 = csub(v[1], v[5]);
  float2 a2 = cadd(v[2], v[6]), a6 = csub(v[2], v[6]);
  float2 a3 = cadd(v[3], v[7]), a7 = csub(v[3], v[7]);
  a5 = cmul(a5, make_float2(RS, (float)S * RS));
  a6 = make_float2(-(float)S * a6.y, (float)S * a6.x);
  a7 = cmul(a7, make_float2(-RS, (float)S * RS));
  float2 b0 = cadd(a0, a2), b2 = csub(a0, a2);
  float2 b1 = cadd(a1, a3), b3 = csub(a1, a3);
  b3 = make_float2(-(float)S * b3.y, (float)S * b3.x);
  v[0] = cadd(b0, b1); v[4] = csub(b0, b1);
  v[2] = cadd(b2, b3); v[6] = csub(b2, b3);
  float2 c0 = cadd(a4, a6), c2 = csub(a4, a6);
  float2 c1 = cadd(a5, a7), c3 = csub(a5, a7);
  c3 = make_float2(-(float)S * c3.y, (float)S * c3.x);
  v[1] = cadd(c0, c1); v[5] = csub(c0, c1);
  v[3] = cadd(c2, c3); v[7] = csub(c2, c3);
}

// Forward 512-pt DIF FFT on two LDS lines (one wave). Natural in, digit-rev out.
__device__ __forceinline__ void fft_fwd_pair(float2* __restrict__ A, float2* __restrict__ B, int l){
  float2 va[8], vb[8];
  #pragma unroll
  for(int j = 0; j < 8; j++){ int s = SL(l + 64*j); va[j] = A[s]; vb[j] = B[s]; }
  dft8<-1>(va); dft8<-1>(vb);
  #pragma unroll
  for(int t = 1; t < 8; t++){
    float sn, cs;
    __sincosf((-6.283185307179586f / 512.0f) * (float)(l * t), &sn, &cs);
    float2 w = make_float2(cs, sn);
    va[t] = cmul(va[t], w); vb[t] = cmul(vb[t], w);
  }
  #pragma unroll
  for(int t = 0; t < 8; t++){ int s = SL(t*64 + l); A[s] = va[t]; B[s] = vb[t]; }
  __syncthreads();
  int tg = l >> 3, m = l & 7;
  #pragma unroll
  for(int j = 0; j < 8; j++){ int s = SL(tg*64 + m + 8*j); va[j] = A[s]; vb[j] = B[s]; }
  dft8<-1>(va); dft8<-1>(vb);
  #pragma unroll
  for(int t = 1; t < 8; t++){
    float sn, cs;
    __sincosf((-6.283185307179586f / 64.0f) * (float)(m * t), &sn, &cs);
    float2 w = make_float2(cs, sn);
    va[t] = cmul(va[t], w); vb[t] = cmul(vb[t], w);
  }
  #pragma unroll
  for(int t = 0; t < 8; t++){ int s = SL(tg*64 + t*8 + m); A[s] = va[t]; B[s] = vb[t]; }
  __syncthreads();
  #pragma unroll
  for(int j = 0; j < 8; j++){ int s = SL(8*l + j); va[j] = A[s]; vb[j] = B[s]; }
  dft8<-1>(va); dft8<-1>(vb);
  #pragma unroll
  for(int t = 0; t < 8; t++){ int s = SL(8*l + t); A[s] = va[t]; B[s] = vb[t]; }
}

// Adjoint 512-pt FFT: digit-rev in, natural out. Exact adjoint of fft_fwd_pair.
__device__ __forceinline__ void fft_inv_pair(float2* __restrict__ A, float2* __restrict__ B, int l){
  float2 va[8], vb[8];
  #pragma unroll
  for(int j = 0; j < 8; j++){ int s = SL(8*l + j); va[j] = A[s]; vb[j] = B[s]; }
  dft8<1>(va); dft8<1>(vb);
  #pragma unroll
  for(int t = 0; t < 8; t++){ int s = SL(8*l + t); A[s] = va[t]; B[s] = vb[t]; }
  __syncthreads();
  int tg = l >> 3, m = l & 7;
  #pragma unroll
  for(int j = 0; j < 8; j++){ int s = SL(tg*64 + 8*j + m); va[j] = A[s]; vb[j] = B[s]; }
  #pragma unroll
  for(int j = 1; j < 8; j++){
    float sn, cs;
    __sincosf((6.283185307179586f / 64.0f) * (float)(m * j), &sn, &cs);
    float2 w = make_float2(cs, sn);
    va[j] = cmul(va[j], w); vb[j] = cmul(vb[j], w);
  }
  dft8<1>(va); dft8<1>(vb);
  #pragma unroll
  for(int j = 0; j < 8; j++){ int s = SL(tg*64 + m + 8*j); A[s] = va[j]; B[s] = vb[j]; }
  __syncthreads();
  #pragma unroll
  for(int t = 0; t < 8; t++){ int s = SL(t*64 + l); va[t] = A[s]; vb[t] = B[s]; }
  #pragma unroll
  for(int t = 1; t < 8; t++){
    float sn, cs;
    __sincosf((6.283185307179586f / 512.0f) * (float)(l * t), &sn, &cs);
    float2 w = make_float2(cs, sn);
    va[t] = cmul(va[t], w); vb[t] = cmul(vb[t], w);
  }
  dft8<1>(va); dft8<1>(vb);
  #pragma unroll
  for(int j = 0; j < 8; j++){ int s = SL(l + 64*j); A[s] = va[j]; B[s] = vb[j]; }
}

// transposed fp16 store of LDS strip: dst element (s<<9)+rr2, rr2 in 0..7 (pairs via uint2)
__device__ __forceinline__ void store_strip_h(const float2* __restrict__ lds, __half2* __restrict__ dst, int t){
  int q = t & 3, s0v = t >> 2;
  #pragma unroll
  for(int k = 0; k < 8; k++){
    int s = s0v + 64 * k;
    float2 v0 = lds[(2*q)   * LSTRIDE + SL(s)];
    float2 v1 = lds[(2*q+1) * LSTRIDE + SL(s)];
    uint2 u; u.x = h2bits(v0); u.y = h2bits(v1);
    *reinterpret_cast<uint2*>(dst + ((size_t)s << 9) + 2*q) = u;
  }
}

// fp16 strip load into LDS: src element (rr<<9)+e, e natural 0..511 (pairs via uint2)
__device__ __forceinline__ void load_strip_h(float2* __restrict__ lds, const __half2* __restrict__ src, int t){
  int rr = t >> 5, col = t & 31;
  #pragma unroll
  for(int k = 0; k < 8; k++){
    int e = 2*col + 64*k;
    uint2 u = *reinterpret_cast<const uint2*>(src + ((size_t)rr << 9) + e);
    lds[rr * LSTRIDE + SL(e)]     = bits2f(u.x);
    lds[rr * LSTRIDE + SL(e + 1)] = bits2f(u.y);
  }
}

// ---------------- prologue: forward row FFT of S*xbar/512 -> U (fp16, transposed) ------------
__global__ __launch_bounds__(256) void k_fwd_rows(const float2* __restrict__ xbar, __half2* __restrict__ U){
  __shared__ float2 lds[NLINES * LSTRIDE];
  int b = blockIdx.x >> 6, r0 = (blockIdx.x & 63) << 3;
  int t = threadIdx.x;
  int rr = t >> 5, col = t & 31;
  const float2* src = xbar + ((size_t)(b * 512 + r0) << 9);
  #pragma unroll
  for(int k = 0; k < 16; k++){
    int c = col + 32 * k;
    float2 v = src[(rr << 9) + c];
    float sc = ((r0 + rr + c) & 1) ? -INV_N : INV_N;
    v.x *= sc; v.y *= sc;
    lds[rr * LSTRIDE + SL(c)] = v;
  }
  __syncthreads();
  int wv = t >> 6, l = t & 63;
  fft_fwd_pair(&lds[wv * LSTRIDE], &lds[(wv + 4) * LSTRIDE], l);
  __syncthreads();
  store_strip_h(lds, U + ((size_t)b << 18) + r0, t);
}

// ---- K_A: column fwd FFT + packed p1 prox + column inv FFT -> V, then fused TV dual (p2) ----
__global__ __launch_bounds__(256) void k_colsA(const __half2* __restrict__ U, __half2* __restrict__ p1p,
                                               const __half2* __restrict__ yp, const int* __restrict__ idx,
                                               const int* __restrict__ cnt, __half2* __restrict__ V,
                                               const float2* __restrict__ xbar, __half2* __restrict__ p2h,
                                               __half2* __restrict__ p2w, const __half* __restrict__ lamh){
  __shared__ float2 lds[NLINES * LSTRIDE];
  int b = blockIdx.x >> 6, cs0 = (blockIdx.x & 63) << 3;
  int t = threadIdx.x;
  int rr = t >> 5, col = t & 31;
  load_strip_h(lds, U + ((size_t)(b * 512 + cs0) << 9), t);
  __syncthreads();
  int wv = t >> 6, l = t & 63;
  fft_fwd_pair(&lds[wv * LSTRIDE], &lds[(wv + 4) * LSTRIDE], l);
  __syncthreads();
  // packed p1 update: line g handles column cs0+g, segment [cs*512, cs*512+cnt[cs])
  int g = rr, lane = col;
  int cs = cs0 + g;
  int jbase = cs << 9;
  int jcnt = cnt[cs];
  size_t boff = (size_t)b * APACK;
  int ksi[16]; float2 pn[16];
  #pragma unroll
  for(int tt = 0; tt < 16; tt++){
    int jj = lane + 32 * tt;
    bool act = jj < jcnt;
    int j = jbase + (act ? jj : 0);
    int ks = act ? idx[j] : 0;
    float2 K = lds[g * LSTRIDE + SL(ks)];
    float2 yv = __half22float2(yp[boff + j]);
    float2 p  = __half22float2(p1p[boff + j]);
    float2 v;
    v.x = (p.x + SIGMA * (K.x - yv.x)) * INV1S;
    v.y = (p.y + SIGMA * (K.y - yv.y)) * INV1S;
    if(act) p1p[boff + j] = __floats2half2_rn(v.x, v.y);
    ksi[tt] = act ? ks : -1;
    pn[tt] = v;
  }
  __syncthreads();
  #pragma unroll
  for(int k = 0; k < 16; k++) lds[rr * LSTRIDE + SL(col + 32 * k)] = make_float2(0.0f, 0.0f);
  __syncthreads();
  #pragma unroll
  for(int tt = 0; tt < 16; tt++) if(ksi[tt] >= 0) lds[g * LSTRIDE + SL(ksi[tt])] = pn[tt];
  __syncthreads();
  fft_inv_pair(&lds[wv * LSTRIDE], &lds[(wv + 4) * LSTRIDE], l);
  __syncthreads();
  store_strip_h(lds, V + ((size_t)b << 18) + cs0, t);

  // ---- fused TV dual update (former k_p2): 4096 elements per block, disjoint from part 1 ----
  int base_i = blockIdx.x << 12;
  #pragma unroll
  for(int k = 0; k < 16; k++){
    int i = base_i + (k << 8) + t;
    int c = i & 511, r = (i >> 9) & 511;
    int idn = (r < 511) ? i + 512 : i - (511 << 9);
    int irt = (c < 511) ? i + 1   : i - 511;
    float2 xc = xbar[i];
    float2 xd = xbar[idn];
    float2 xr = xbar[irt];
    float lv = __half2float(lamh[i]);
    float2 qh = __half22float2(p2h[i]);
    float2 qw = __half22float2(p2w[i]);
    qh.x += SIGMA * (xd.x - xc.x); qh.y += SIGMA * (xd.y - xc.y);
    qw.x += SIGMA * (xr.x - xc.x); qw.y += SIGMA * (xr.y - xc.y);
    qh.x = fminf(fmaxf(qh.x, -lv), lv); qh.y = fminf(fmaxf(qh.y, -lv), lv);
    qw.x = fminf(fmaxf(qw.x, -lv), lv); qw.y = fminf(fmaxf(qw.y, -lv), lv);
    p2h[i] = __floats2half2_rn(qh.x, qh.y);
    p2w[i] = __floats2half2_rn(qw.x, qw.y);
  }
}

// ------- K_B: row IFFT + S/512 + divergence + primal update + row FFT -> U -------------------
__global__ __launch_bounds__(256) void k_megaB(const __half2* __restrict__ V, const __half2* __restrict__ p2h,
                                               const __half2* __restrict__ p2w, float2* __restrict__ x,
                                               float2* __restrict__ xbar, __half2* __restrict__ U, int last){
  __shared__ float2 lds[NLINES * LSTRIDE];
  int b = blockIdx.x >> 6, r0 = (blockIdx.x & 63) << 3;
  int t = threadIdx.x;
  int rr = t >> 5, col = t & 31;
  load_strip_h(lds, V + ((size_t)(b * 512 + r0) << 9), t);
  __syncthreads();
  int wv = t >> 6, l = t & 63;
  fft_inv_pair(&lds[wv * LSTRIDE], &lds[(wv + 4) * LSTRIDE], l);
  __syncthreads();
  int r = r0 + rr;
  size_t base   = ((size_t)(b * 512 + r) << 9);
  size_t baseUp = ((size_t)(b * 512 + ((r - 1) & 511)) << 9);
  #pragma unroll
  for(int k = 0; k < 16; k++){
    int c = col + 32 * k;
    int cl = (c - 1) & 511;
    float2 v = lds[rr * LSTRIDE + SL(c)];
    float sc = ((r + c) & 1) ? -INV_N : INV_N;
    float2 ph  = __half22float2(p2h[base + c]);
    float2 phu = __half22float2(p2h[baseUp + c]);
    float2 pw  = __half22float2(p2w[base + c]);
    float2 pwl = __half22float2(p2w[base + cl]);
    float gx = sc * v.x + (phu.x - ph.x) + (pwl.x - pw.x);
    float gy = sc * v.y + (phu.y - ph.y) + (pwl.y - pw.y);
    float2 xo = x[base + c];
    float2 xn = make_float2(xo.x - TAU * gx, xo.y - TAU * gy);
    x[base + c] = xn;
    float2 xb2 = make_float2(2.0f * xn.x - xo.x, 2.0f * xn.y - xo.y);
    xbar[base + c] = xb2;
    lds[rr * LSTRIDE + SL(c)] = make_float2(sc * xb2.x, sc * xb2.y);  // S*xbar/512 for next fwd FFT
  }
  if(last) return;
  __syncthreads();
  fft_fwd_pair(&lds[wv * LSTRIDE], &lds[(wv + 4) * LSTRIDE], l);
  __syncthreads();
  store_strip_h(lds, U + ((size_t)b << 18) + r0, t);
}

// ---------------- init kernels ---------------------------------------------------------------
__global__ __launch_bounds__(256) void k_init_x(const float* __restrict__ ir, const float* __restrict__ ii,
                                                float2* __restrict__ x, float2* __restrict__ xbar){
  int i = blockIdx.x * 256 + threadIdx.x;
  float2 v = make_float2(ir[i], ii[i]);
  x[i] = v; xbar[i] = v;
}

__global__ __launch_bounds__(256) void k_init_lam(const float* __restrict__ lam, __half* __restrict__ lamh){
  int i = blockIdx.x * 256 + threadIdx.x;
  lamh[i] = __float2half(lam[i]);
}

// Build per-column packed index list + packed y' (digit-rev, S-folded, fp16) for active entries.
__global__ __launch_bounds__(256) void k_pack(const int* __restrict__ mask, const float* __restrict__ kr,
                                              const float* __restrict__ ki, int* __restrict__ idx,
                                              int* __restrict__ cnt, __half2* __restrict__ yp){
  __shared__ int wcnt[8];
  int cs = blockIdx.x;
  int t = threadIdx.x, lane = t & 63, wv = t >> 6;
  int csr = rev9(cs);
  int jbase = cs << 9;
  #pragma unroll
  for(int rnd = 0; rnd < 2; rnd++){
    int ks = t + 256 * rnd;
    int ksr = rev9(ks);
    int pred = (mask[(ksr << 9) + csr] != 0) ? 1 : 0;
    unsigned long long bal = __ballot(pred);
    if(lane == 0) wcnt[4 * rnd + wv] = (int)__popcll(bal);
    __syncthreads();
    int pre = 0;
    for(int w = 0; w < wv; w++) pre += wcnt[4 * rnd + w];
    int roundbase = (rnd == 1) ? (wcnt[0] + wcnt[1] + wcnt[2] + wcnt[3]) : 0;
    int lpre = (int)__popcll(bal & ((1ull << lane) - 1ull));
    if(pred){
      int pos = jbase + roundbase + pre + lpre;
      idx[pos] = ks;
      float s = ((ksr + csr) & 1) ? -1.0f : 1.0f;
      for(int b = 0; b < 16; b++){
        size_t a = ((size_t)b << 18) + ((size_t)ksr << 9) + csr;
        yp[(size_t)b * APACK + pos] = __floats2half2_rn(s * kr[a], s * ki[a]);
      }
    }
    __syncthreads();
  }
  if(t == 0) cnt[cs] = wcnt[0] + wcnt[1] + wcnt[2] + wcnt[3] + wcnt[4] + wcnt[5] + wcnt[6] + wcnt[7];
}

// ---------------- launcher -------------------------------------------------------------------
extern "C" void kernel_launch(void* const* d_in, const int* in_sizes, int n_in,
                              void* d_out, int out_size, void* d_ws, size_t ws_size,
                              hipStream_t stream){
  const float* ir  = (const float*)d_in[0];
  const float* ii  = (const float*)d_in[1];
  const float* kdr = (const float*)d_in[2];
  const float* kdi = (const float*)d_in[3];
  const float* lam = (const float*)d_in[4];
  const int*  mask = (const int*)d_in[5];
  float2* x = (float2*)d_out;

  char* ws = (char*)d_ws;
  __half2* p1p  = (__half2*)ws;                     // 16 MB cap
  __half2* yp   = p1p + (size_t)APACK * 16;         // 16 MB cap
  __half2* p2h  = yp  + (size_t)APACK * 16;         // 16 MB
  __half2* p2w  = p2h + NT;                         // 16 MB
  __half2* U    = p2w + NT;                         // 16 MB
  __half2* V    = U   + NT;                         // 16 MB
  float2*  xbar = (float2*)(V + NT);                // 32 MB
  __half*  lamh = (__half*)(xbar + NT);             // 8 MB
  int*     idx  = (int*)(lamh + NT);                // 1 MB
  int*     cnt  = idx + APACK;                      // 2 KB
  // total ws use: ~137 MB

  hipMemsetAsync(p1p, 0, (size_t)APACK * 16 * sizeof(__half2), stream);   // p1 = 0
  hipMemsetAsync(p2h, 0, (size_t)2 * NT * sizeof(__half2), stream);       // p2h + p2w = 0
  k_pack<<<512, 256, 0, stream>>>(mask, kdr, kdi, idx, cnt, yp);
  k_init_lam<<<NT / 256, 256, 0, stream>>>(lam, lamh);
  k_init_x<<<NT / 256, 256, 0, stream>>>(ir, ii, x, xbar);
  k_fwd_rows<<<1024, 256, 0, stream>>>(xbar, U);

  for(int it = 0; it < 128; it++){
    k_colsA<<<1024, 256, 0, stream>>>(U, p1p, yp, idx, cnt, V, xbar, p2h, p2w, lamh);
    k_megaB<<<1024, 256, 0, stream>>>(V, p2h, p2w, x, xbar, U, it == 127 ? 1 : 0);
  }
}

// Round 4
// 7306.687 us; speedup vs baseline: 2.0542x; 1.1572x over previous
//
#include <hip/hip_runtime.h>
#include <hip/hip_fp16.h>
#include <cstddef>

#define NBATCH 16
#define NSIDE  512
#define NT     (NBATCH * NSIDE * NSIDE)   // 4,194,304 complex elements per field
#define NLINES 8                           // FFT lines per workgroup
#define LSTRIDE 577                        // padded float2 stride per line in LDS
#define APACK  (512 * 512)                 // packed capacity (worst case all-active)

constexpr float SIGMA = (float)(0.97 / 3.0);
constexpr float TAU   = (float)(0.97 / 3.0);
constexpr float INV1S = (float)(1.0 / (1.0 + 0.97 / 3.0));
constexpr float INV_N = 1.0f / 512.0f;

// ---------- complex helpers ----------
__device__ __forceinline__ float2 cadd(float2 a, float2 b){ return make_float2(a.x+b.x, a.y+b.y); }
__device__ __forceinline__ float2 csub(float2 a, float2 b){ return make_float2(a.x-b.x, a.y-b.y); }
__device__ __forceinline__ float2 cmul(float2 a, float2 b){ return make_float2(a.x*b.x - a.y*b.y, a.x*b.y + a.y*b.x); }

// padded LDS slot: +1 float2 every 8 slots
__device__ __forceinline__ int SL(int s){ return s + (s >> 3); }
// base-8 3-digit reversal of a 9-bit index
__device__ __forceinline__ int rev9(int s){ return ((s & 7) << 6) | (s & 56) | (s >> 6); }

// fp16 pack/unpack
__device__ __forceinline__ unsigned h2bits(float2 v){
  __half2 h = __floats2half2_rn(v.x, v.y);
  return *reinterpret_cast<unsigned*>(&h);
}
__device__ __forceinline__ float2 bits2f(unsigned u){
  __half2 h = *reinterpret_cast<__half2*>(&u);
  return __half22float2(h);
}

template<int S>
__device__ __forceinline__ void dft8(float2 v[8]){
  const float RS = 0.70710678118654752440f;
  float2 a0 = cadd(v[0], v[4]), a4 = csub(v[0], v[4]);
  float2 a1 = cadd(v[1], v[5]), a5 = csub(v[1], v[5]);
  float2 a2 = cadd(v[2], v[6]), a6 = csub(v[2], v[6]);
  float2 a3 = cadd(v[3], v[7]), a7 = csub(v[3], v[7]);
  a5 = cmul(a5, make_float2(RS, (float)S * RS));
  a6 = make_float2(-(float)S * a6.y, (float)S * a6.x);
  a7 = cmul(a7, make_float2(-RS, (float)S * RS));
  float2 b0 = cadd(a0, a2), b2 = csub(a0, a2);
  float2 b1 = cadd(a1, a3), b3 = csub(a1, a3);
  b3 = make_float2(-(float)S * b3.y, (float)S * b3.x);
  v[0] = cadd(b0, b1); v[4] = csub(b0, b1);
  v[2] = cadd(b2, b3); v[6] = csub(b2, b3);
  float2 c0 = cadd(a4, a6), c2 = csub(a4, a6);
  float2 c1 = cadd(a5, a7), c3 = csub(a5, a7);
  c3 = make_float2(-(float)S * c3.y, (float)S * c3.x);
  v[1] = cadd(c0, c1); v[5] = csub(c0, c1);
  v[3] = cadd(c2, c3); v[7] = csub(c2, c3);
}

// Forward 512-pt DIF FFT on two LDS lines (one wave). Natural in, digit-rev out.
__device__ __forceinline__ void fft_fwd_pair(float2* __restrict__ A, float2* __restrict__ B, int l){
  float2 va[8], vb[8];
  #pragma unroll
  for(int j = 0; j < 8; j++){ int s = SL(l + 64*j); va[j] = A[s]; vb[j] = B[s]; }
  dft8<-1>(va); dft8<-1>(vb);
  #pragma unroll
  for(int t = 1; t < 8; t++){
    float sn, cs;
    __sincosf((-6.283185307179586f / 512.0f) * (float)(l * t), &sn, &cs);
    float2 w = make_float2(cs, sn);
    va[t] = cmul(va[t], w); vb[t] = cmul(vb[t], w);
  }
  #pragma unroll
  for(int t = 0; t < 8; t++){ int s = SL(t*64 + l); A[s] = va[t]; B[s] = vb[t]; }
  __syncthreads();
  int tg = l >> 3, m = l & 7;
  #pragma unroll
  for(int j = 0; j < 8; j++){ int s = SL(tg*64 + m + 8*j); va[j] = A[s]; vb[j] = B[s]; }
  dft8<-1>(va); dft8<-1>(vb);
  #pragma unroll
  for(int t = 1; t < 8; t++){
    float sn, cs;
    __sincosf((-6.283185307179586f / 64.0f) * (float)(m * t), &sn, &cs);
    float2 w = make_float2(cs, sn);
    va[t] = cmul(va[t], w); vb[t] = cmul(vb[t], w);
  }
  #pragma unroll
  for(int t = 0; t < 8; t++){ int s = SL(tg*64 + t*8 + m); A[s] = va[t]; B[s] = vb[t]; }
  __syncthreads();
  #pragma unroll
  for(int j = 0; j < 8; j++){ int s = SL(8*l + j); va[j] = A[s]; vb[j] = B[s]; }
  dft8<-1>(va); dft8<-1>(vb);
  #pragma unroll
  for(int t = 0; t < 8; t++){ int s = SL(8*l + t); A[s] = va[t]; B[s] = vb[t]; }
}

// Adjoint 512-pt FFT: digit-rev in, natural out. Exact adjoint of fft_fwd_pair.
__device__ __forceinline__ void fft_inv_pair(float2* __restrict__ A, float2* __restrict__ B, int l){
  float2 va[8], vb[8];
  #pragma unroll
  for(int j = 0; j < 8; j++){ int s = SL(8*l + j); va[j] = A[s]; vb[j] = B[s]; }
  dft8<1>(va); dft8<1>(vb);
  #pragma unroll
  for(int t = 0; t < 8; t++){ int s = SL(8*l + t); A[s] = va[t]; B[s] = vb[t]; }
  __syncthreads();
  int tg = l >> 3, m = l & 7;
  #pragma unroll
  for(int j = 0; j < 8; j++){ int s = SL(tg*64 + 8*j + m); va[j] = A[s]; vb[j] = B[s]; }
  #pragma unroll
  for(int j = 1; j < 8; j++){
    float sn, cs;
    __sincosf((6.283185307179586f / 64.0f) * (float)(m * j), &sn, &cs);
    float2 w = make_float2(cs, sn);
    va[j] = cmul(va[j], w); vb[j] = cmul(vb[j], w);
  }
  dft8<1>(va); dft8<1>(vb);
  #pragma unroll
  for(int j = 0; j < 8; j++){ int s = SL(tg*64 + m + 8*j); A[s] = va[j]; B[s] = vb[j]; }
  __syncthreads();
  #pragma unroll
  for(int t = 0; t < 8; t++){ int s = SL(t*64 + l); va[t] = A[s]; vb[t] = B[s]; }
  #pragma unroll
  for(int t = 1; t < 8; t++){
    float sn, cs;
    __sincosf((6.283185307179586f / 512.0f) * (float)(l * t), &sn, &cs);
    float2 w = make_float2(cs, sn);
    va[t] = cmul(va[t], w); vb[t] = cmul(vb[t], w);
  }
  dft8<1>(va); dft8<1>(vb);
  #pragma unroll
  for(int j = 0; j < 8; j++){ int s = SL(l + 64*j); A[s] = va[j]; B[s] = vb[j]; }
}

// Blocked-tile store: tile holds 512 x 8 fp16 complex, element s*8 + line.
// Per wave each store instruction covers 512B contiguous.
__device__ __forceinline__ void store_strip_blk(const float2* __restrict__ lds, __half2* __restrict__ tile, int t){
  int q = t & 3, s0v = t >> 2;   // s0v 0..63
  #pragma unroll
  for(int k = 0; k < 8; k++){
    int s = s0v + 64 * k;
    float2 v0 = lds[(2*q)   * LSTRIDE + SL(s)];
    float2 v1 = lds[(2*q+1) * LSTRIDE + SL(s)];
    uint2 u; u.x = h2bits(v0); u.y = h2bits(v1);
    *reinterpret_cast<uint2*>(tile + s*8 + 2*q) = u;
  }
}

// Blocked-tile load into LDS lines: 64 tiles of 512x8; line g reads tile row (lineBase+g),
// natural index n = tile*8 + intra.  uint4 = 4 complex; 256B contiguous per 16 lanes.
__device__ __forceinline__ void load_strip_blk(float2* __restrict__ lds, const __half2* __restrict__ base,
                                               int lineBase, int t){
  #pragma unroll
  for(int k = 0; k < 4; k++){
    int idx = t + 256 * k;        // 0..1023
    int tb = idx >> 4;            // tile 0..63
    int rem = idx & 15;
    int g = rem >> 1, h = rem & 1;
    uint4 u = *reinterpret_cast<const uint4*>(base + ((size_t)tb << 12) + ((lineBase + g) << 3) + (h << 2));
    int n = (tb << 3) + (h << 2);
    lds[g * LSTRIDE + SL(n)]     = bits2f(u.x);
    lds[g * LSTRIDE + SL(n + 1)] = bits2f(u.y);
    lds[g * LSTRIDE + SL(n + 2)] = bits2f(u.z);
    lds[g * LSTRIDE + SL(n + 3)] = bits2f(u.w);
  }
}

// ---------------- prologue: forward row FFT of S*x0/512 -> U (fp16, blocked) -----------------
__global__ __launch_bounds__(256) void k_fwd_rows(const float* __restrict__ ir, const float* __restrict__ ii,
                                                  __half2* __restrict__ U){
  __shared__ float2 lds[NLINES * LSTRIDE];
  int b = blockIdx.x >> 6, rb = blockIdx.x & 63, r0 = rb << 3;
  int t = threadIdx.x;
  int rr = t >> 5, col = t & 31;
  size_t base = ((size_t)(b * 512 + r0 + rr) << 9);
  #pragma unroll
  for(int k = 0; k < 16; k++){
    int c = col + 32 * k;
    float sc = ((r0 + rr + c) & 1) ? -INV_N : INV_N;
    lds[rr * LSTRIDE + SL(c)] = make_float2(sc * ir[base + c], sc * ii[base + c]);
  }
  __syncthreads();
  int wv = t >> 6, l = t & 63;
  fft_fwd_pair(&lds[wv * LSTRIDE], &lds[(wv + 4) * LSTRIDE], l);
  __syncthreads();
  store_strip_blk(lds, U + ((size_t)(b * 64 + rb) << 12), t);
}

// ---- K_A: column fwd FFT + packed p1 prox + column inv FFT -> V, then fused TV dual (p2) ----
__global__ __launch_bounds__(256) void k_colsA(const __half2* __restrict__ U, __half2* __restrict__ p1p,
                                               const __half2* __restrict__ yp, const int* __restrict__ idx,
                                               const int* __restrict__ cnt, __half2* __restrict__ V,
                                               const __half2* __restrict__ xbarh, __half2* __restrict__ p2h,
                                               __half2* __restrict__ p2w, const __half* __restrict__ lamh){
  __shared__ float2 lds[NLINES * LSTRIDE];
  int b = blockIdx.x >> 6, cb = blockIdx.x & 63, cs0 = cb << 3;
  int t = threadIdx.x;
  int rr = t >> 5, col = t & 31;
  load_strip_blk(lds, U + ((size_t)b << 18), cs0, t);
  __syncthreads();
  int wv = t >> 6, l = t & 63;
  fft_fwd_pair(&lds[wv * LSTRIDE], &lds[(wv + 4) * LSTRIDE], l);
  __syncthreads();
  // packed p1 update: line g handles column cs0+g, segment [cs*512, cs*512+cnt[cs])
  int g = rr, lane = col;
  int cs = cs0 + g;
  int jbase = cs << 9;
  int jcnt = cnt[cs];
  size_t boff = (size_t)b * APACK;
  int ksi[16]; float2 pn[16];
  #pragma unroll
  for(int tt = 0; tt < 16; tt++){
    int jj = lane + 32 * tt;
    bool act = jj < jcnt;
    int j = jbase + (act ? jj : 0);
    int ks = act ? idx[j] : 0;
    float2 K = lds[g * LSTRIDE + SL(ks)];
    float2 yv = __half22float2(yp[boff + j]);
    float2 p  = __half22float2(p1p[boff + j]);
    float2 v;
    v.x = (p.x + SIGMA * (K.x - yv.x)) * INV1S;
    v.y = (p.y + SIGMA * (K.y - yv.y)) * INV1S;
    if(act) p1p[boff + j] = __floats2half2_rn(v.x, v.y);
    ksi[tt] = act ? ks : -1;
    pn[tt] = v;
  }
  __syncthreads();
  #pragma unroll
  for(int k = 0; k < 16; k++) lds[rr * LSTRIDE + SL(col + 32 * k)] = make_float2(0.0f, 0.0f);
  __syncthreads();
  #pragma unroll
  for(int tt = 0; tt < 16; tt++) if(ksi[tt] >= 0) lds[g * LSTRIDE + SL(ksi[tt])] = pn[tt];
  __syncthreads();
  fft_inv_pair(&lds[wv * LSTRIDE], &lds[(wv + 4) * LSTRIDE], l);
  __syncthreads();
  store_strip_blk(lds, V + ((size_t)(b * 64 + cb) << 12), t);

  // ---- fused TV dual update: 4096 elements per block, disjoint from part 1 ----
  int base_i = blockIdx.x << 12;
  #pragma unroll
  for(int k = 0; k < 16; k++){
    int i = base_i + (k << 8) + t;
    int c = i & 511, r = (i >> 9) & 511;
    int idn = (r < 511) ? i + 512 : i - (511 << 9);
    int irt = (c < 511) ? i + 1   : i - 511;
    float2 xc = __half22float2(xbarh[i]);
    float2 xd = __half22float2(xbarh[idn]);
    float2 xr = __half22float2(xbarh[irt]);
    float lv = __half2float(lamh[i]);
    float2 qh = __half22float2(p2h[i]);
    float2 qw = __half22float2(p2w[i]);
    qh.x += SIGMA * (xd.x - xc.x); qh.y += SIGMA * (xd.y - xc.y);
    qw.x += SIGMA * (xr.x - xc.x); qw.y += SIGMA * (xr.y - xc.y);
    qh.x = fminf(fmaxf(qh.x, -lv), lv); qh.y = fminf(fmaxf(qh.y, -lv), lv);
    qw.x = fminf(fmaxf(qw.x, -lv), lv); qw.y = fminf(fmaxf(qw.y, -lv), lv);
    p2h[i] = __floats2half2_rn(qh.x, qh.y);
    p2w[i] = __floats2half2_rn(qw.x, qw.y);
  }
}

// ------- K_B: row IFFT + S/512 + divergence + primal update + row FFT -> U -------------------
__global__ __launch_bounds__(256) void k_megaB(const __half2* __restrict__ V, const __half2* __restrict__ p2h,
                                               const __half2* __restrict__ p2w, float2* __restrict__ x,
                                               __half2* __restrict__ xbarh, __half2* __restrict__ U, int last){
  __shared__ float2 lds[NLINES * LSTRIDE];
  int b = blockIdx.x >> 6, rb = blockIdx.x & 63, r0 = rb << 3;
  int t = threadIdx.x;
  int rr = t >> 5, col = t & 31;
  load_strip_blk(lds, V + ((size_t)b << 18), r0, t);
  __syncthreads();
  int wv = t >> 6, l = t & 63;
  fft_inv_pair(&lds[wv * LSTRIDE], &lds[(wv + 4) * LSTRIDE], l);
  __syncthreads();
  int r = r0 + rr;
  size_t base   = ((size_t)(b * 512 + r) << 9);
  size_t baseUp = ((size_t)(b * 512 + ((r - 1) & 511)) << 9);
  #pragma unroll
  for(int k = 0; k < 16; k++){
    int c = col + 32 * k;
    int cl = (c - 1) & 511;
    float2 v = lds[rr * LSTRIDE + SL(c)];
    float sc = ((r + c) & 1) ? -INV_N : INV_N;
    float2 ph  = __half22float2(p2h[base + c]);
    float2 phu = __half22float2(p2h[baseUp + c]);
    float2 pw  = __half22float2(p2w[base + c]);
    float2 pwl = __half22float2(p2w[base + cl]);
    float gx = sc * v.x + (phu.x - ph.x) + (pwl.x - pw.x);
    float gy = sc * v.y + (phu.y - ph.y) + (pwl.y - pw.y);
    float2 xo = x[base + c];
    float2 xn = make_float2(xo.x - TAU * gx, xo.y - TAU * gy);
    x[base + c] = xn;
    float2 xb2 = make_float2(2.0f * xn.x - xo.x, 2.0f * xn.y - xo.y);
    xbarh[base + c] = __floats2half2_rn(xb2.x, xb2.y);
    lds[rr * LSTRIDE + SL(c)] = make_float2(sc * xb2.x, sc * xb2.y);  // S*xbar/512 for next fwd FFT
  }
  if(last) return;
  __syncthreads();
  fft_fwd_pair(&lds[wv * LSTRIDE], &lds[(wv + 4) * LSTRIDE], l);
  __syncthreads();
  store_strip_blk(lds, U + ((size_t)(b * 64 + rb) << 12), t);
}

// ---------------- init kernels ---------------------------------------------------------------
__global__ __launch_bounds__(256) void k_init_x(const float* __restrict__ ir, const float* __restrict__ ii,
                                                float2* __restrict__ x, __half2* __restrict__ xbarh){
  int i = blockIdx.x * 256 + threadIdx.x;
  float vr = ir[i], vi = ii[i];
  x[i] = make_float2(vr, vi);
  xbarh[i] = __floats2half2_rn(vr, vi);
}

__global__ __launch_bounds__(256) void k_init_lam(const float* __restrict__ lam, __half* __restrict__ lamh){
  int i = blockIdx.x * 256 + threadIdx.x;
  lamh[i] = __float2half(lam[i]);
}

// Build per-column packed index list + packed y' (digit-rev, S-folded, fp16) for active entries.
__global__ __launch_bounds__(256) void k_pack(const int* __restrict__ mask, const float* __restrict__ kr,
                                              const float* __restrict__ ki, int* __restrict__ idx,
                                              int* __restrict__ cnt, __half2* __restrict__ yp){
  __shared__ int wcnt[8];
  int cs = blockIdx.x;
  int t = threadIdx.x, lane = t & 63, wv = t >> 6;
  int csr = rev9(cs);
  int jbase = cs << 9;
  #pragma unroll
  for(int rnd = 0; rnd < 2; rnd++){
    int ks = t + 256 * rnd;
    int ksr = rev9(ks);
    int pred = (mask[(ksr << 9) + csr] != 0) ? 1 : 0;
    unsigned long long bal = __ballot(pred);
    if(lane == 0) wcnt[4 * rnd + wv] = (int)__popcll(bal);
    __syncthreads();
    int pre = 0;
    for(int w = 0; w < wv; w++) pre += wcnt[4 * rnd + w];
    int roundbase = (rnd == 1) ? (wcnt[0] + wcnt[1] + wcnt[2] + wcnt[3]) : 0;
    int lpre = (int)__popcll(bal & ((1ull << lane) - 1ull));
    if(pred){
      int pos = jbase + roundbase + pre + lpre;
      idx[pos] = ks;
      float s = ((ksr + csr) & 1) ? -1.0f : 1.0f;
      for(int b = 0; b < 16; b++){
        size_t a = ((size_t)b << 18) + ((size_t)ksr << 9) + csr;
        yp[(size_t)b * APACK + pos] = __floats2half2_rn(s * kr[a], s * ki[a]);
      }
    }
    __syncthreads();
  }
  if(t == 0) cnt[cs] = wcnt[0] + wcnt[1] + wcnt[2] + wcnt[3] + wcnt[4] + wcnt[5] + wcnt[6] + wcnt[7];
}

// ---------------- launcher -------------------------------------------------------------------
extern "C" void kernel_launch(void* const* d_in, const int* in_sizes, int n_in,
                              void* d_out, int out_size, void* d_ws, size_t ws_size,
                              hipStream_t stream){
  const float* ir  = (const float*)d_in[0];
  const float* ii  = (const float*)d_in[1];
  const float* kdr = (const float*)d_in[2];
  const float* kdi = (const float*)d_in[3];
  const float* lam = (const float*)d_in[4];
  const int*  mask = (const int*)d_in[5];
  float2* x = (float2*)d_out;

  char* ws = (char*)d_ws;
  __half2* p1p   = (__half2*)ws;                     // 16 MB cap
  __half2* yp    = p1p + (size_t)APACK * 16;         // 16 MB cap
  __half2* p2h   = yp  + (size_t)APACK * 16;         // 16 MB
  __half2* p2w   = p2h + NT;                         // 16 MB
  __half2* U     = p2w + NT;                         // 16 MB (blocked tiles)
  __half2* V     = U   + NT;                         // 16 MB (blocked tiles)
  __half2* xbarh = V   + NT;                         // 16 MB
  __half*  lamh  = (__half*)(xbarh + NT);            // 8 MB
  int*     idx   = (int*)(lamh + NT);                // 1 MB
  int*     cnt   = idx + APACK;                      // 2 KB
  // total ws use: ~121 MB

  hipMemsetAsync(p1p, 0, (size_t)APACK * 16 * sizeof(__half2), stream);   // p1 = 0
  hipMemsetAsync(p2h, 0, (size_t)2 * NT * sizeof(__half2), stream);       // p2h + p2w = 0
  k_pack<<<512, 256, 0, stream>>>(mask, kdr, kdi, idx, cnt, yp);
  k_init_lam<<<NT / 256, 256, 0, stream>>>(lam, lamh);
  k_init_x<<<NT / 256, 256, 0, stream>>>(ir, ii, x, xbarh);
  k_fwd_rows<<<1024, 256, 0, stream>>>(ir, ii, U);

  for(int it = 0; it < 128; it++){
    k_colsA<<<1024, 256, 0, stream>>>(U, p1p, yp, idx, cnt, V, xbarh, p2h, p2w, lamh);
    k_megaB<<<1024, 256, 0, stream>>>(V, p2h, p2w, x, xbarh, U, it == 127 ? 1 : 0);
  }
}